// Round 3
// baseline (664.759 us; speedup 1.0000x reference)
//
#include <hip/hip_runtime.h>
#include <math.h>

#define E 100
#define V 3
#define S 100
#define T 10
#define NB 8192
#define SCALE 0.1f
#define PADV  (-4294967295.0f)

// ws float offsets (prep outputs) — total 716 floats
#define WS_H  0     // [3][100]  H = SCALE * (of2 @ W1)
#define WS_G  304   // [3][100]  G = SCALE * (of3 @ W4)
#define WS_B1 608   // [100]     fc1_b passthrough
#define WS_C1 708   // [3]       SCALE * of2·b1
#define WS_C2 712   // [3]       SCALE * of3·b4

// Algebra: of1/of4 are never materialized.
//   m1[s,v]  = x[s,:]·H[v,:] + c1[v]          (masked -> PADV, softmax over s)
//   y[v,k]   = sum_s sm1[s,v] * x[s,k]
//   ws1[v,e] = y[v,:]·W1[e,:] + b1[e]          (since sum_s sm1 == 1 exactly)
//   m2[t,v]  = tag[t,:]·G[v,:] + c2[v]         (softmax over t)
//   out[t]   = sum_v sm2[t,v] * (ws1[v,:]·tag[t,:])
//
// R2/R3: no xs LDS staging. x[b] (40KB) is read twice from global:
//   phase1 row-per-thread (L1-line friendly), y-phase column-coalesced (L2-hot).
// LDS 52KB -> ~12KB; __launch_bounds__(256,8) -> 8 blocks/CU (was 2.66).

__global__ __launch_bounds__(256) void prep_kernel(const float* __restrict__ vk,
        const float* __restrict__ fc1w, const float* __restrict__ fc1b,
        const float* __restrict__ fc2w, const float* __restrict__ fc2b,
        const float* __restrict__ fc3w, const float* __restrict__ fc3b,
        const float* __restrict__ fc4w, const float* __restrict__ fc4b,
        float* __restrict__ ws)
{
    __shared__ __align__(16) float wsm[E * E];   // W1 (blk 0) or W4 (blk 1)
    __shared__ __align__(16) float ofs[V * E];   // of2 (blk 0) or of3 (blk 1)
    const int t   = threadIdx.x;
    const int blk = blockIdx.x;                  // 0: H/c1/b1 path, 1: G/c2 path
    const float* WA = blk ? fc4w : fc1w;
    const float* WB = blk ? fc3w : fc2w;
    const float* bB = blk ? fc3b : fc2b;
    const float* bA = blk ? fc4b : fc1b;

    for (int i = t; i < E * E / 4; i += 256)      // stage WA into LDS
        *(float4*)(&wsm[4 * i]) = *(const float4*)(WA + 4 * i);

    for (int o = t; o < V * E; o += 256) {        // of[v][e] = vk[v,:]·WB[e,:] + bB[e]
        int v = o / E, e = o % E;
        const float* vr = vk + v * E;
        const float* wr = WB + e * E;
        float acc = bB[e];
        for (int k = 0; k < E; k += 4) {
            float4 a = *(const float4*)(vr + k);
            float4 w = *(const float4*)(wr + k);
            acc += a.x * w.x + a.y * w.y + a.z * w.z + a.w * w.w;
        }
        ofs[o] = acc;
    }
    __syncthreads();

    for (int o = t; o < V * E; o += 256) {        // H/G[v][k] = SCALE * sum_e of[v][e]*WA[e][k]
        int v = o / E, k = o % E;
        float acc = 0.f;
        for (int e = 0; e < E; ++e) acc += ofs[v * E + e] * wsm[e * E + k];
        ws[(blk ? WS_G : WS_H) + o] = acc * SCALE;
    }
    if (t < V) {                                   // c[v] = SCALE * sum_e bA[e]*of[v][e]
        float acc = 0.f;
        for (int e = 0; e < E; ++e) acc += bA[e] * ofs[t * E + e];
        ws[(blk ? WS_C2 : WS_C1) + t] = acc * SCALE;
    }
    if (blk == 0 && t < E) ws[WS_B1 + t] = fc1b[t];
}

__global__ __launch_bounds__(256, 8) void mvke_main(const float* __restrict__ x,
        const float* __restrict__ tag, const float* __restrict__ fc1w,
        const float* __restrict__ ws, float* __restrict__ out)
{
    __shared__ __align__(16) float tg[T * E];      // 1000 f
    __shared__ __align__(16) float Hs[V * E];      // 300 f
    __shared__ __align__(16) float Gs[V * E];      // 300 f
    __shared__ __align__(16) float b1s[E];         // 100 f
    __shared__ float cs[8];                         // c1 in [0..2], c2 in [4..6]
    __shared__ __align__(16) float m1s[V * S];     // [v][s]
    __shared__ __align__(16) float sm1s[V * S];    // [v][s]
    __shared__ __align__(16) float ys[V * E];      // [v][k]
    __shared__ __align__(16) float ws1s[V * E];    // [v][e]
    __shared__ float m2s[T * V];                    // [t*3+v]
    __shared__ float sm2s[T * V];
    __shared__ float p3[32];
    // total ~3000 floats = 12KB -> wave-limited 8 blocks/CU

    const int t = threadIdx.x;
    const int b = blockIdx.x;
    const float* xb = x   + (size_t)b * (S * E);
    const float* tb = tag + (size_t)b * (T * E);

    // ---- stage tag (coalesced float4) + small precomputed arrays ----
    for (int i = t; i < T * E / 4; i += 256)       // 250 float4s
        *(float4*)(&tg[4 * i]) = *(const float4*)(tb + 4 * i);
    if (t < 75)        *(float4*)(&Hs[4 * t])          = *(const float4*)(ws + WS_H  + 4 * t);
    else if (t < 150)  *(float4*)(&Gs[4 * (t - 75)])   = *(const float4*)(ws + WS_G  + 4 * (t - 75));
    else if (t < 175)  *(float4*)(&b1s[4 * (t - 150)]) = *(const float4*)(ws + WS_B1 + 4 * (t - 150));
    else if (t < 183)  cs[t - 175] = ws[WS_C1 + (t - 175)];
    __syncthreads();

    // ---- phase 1: m1 rows (t<100, row-per-thread global x) ; m2 on wave 2 ----
    if (t < S) {
        const float* xr = xb + t * E;
        float a0 = cs[0], a1 = cs[1], a2 = cs[2], ra = 0.f;
        #pragma unroll 5
        for (int k = 0; k < E; k += 4) {
            float4 xv = *(const float4*)(xr + k);
            float4 h0 = *(const float4*)(&Hs[k]);
            float4 h1 = *(const float4*)(&Hs[E + k]);
            float4 h2 = *(const float4*)(&Hs[2 * E + k]);
            a0 += xv.x * h0.x + xv.y * h0.y + xv.z * h0.z + xv.w * h0.w;
            a1 += xv.x * h1.x + xv.y * h1.y + xv.z * h1.z + xv.w * h1.w;
            a2 += xv.x * h2.x + xv.y * h2.y + xv.z * h2.z + xv.w * h2.w;
            ra += fabsf(xv.x) + fabsf(xv.y) + fabsf(xv.z) + fabsf(xv.w);
        }
        bool z = (ra == 0.f);
        m1s[t]         = z ? PADV : a0;
        m1s[S + t]     = z ? PADV : a1;
        m1s[2 * S + t] = z ? PADV : a2;
    } else if (t >= 128 && t < 128 + T * V) {
        int o = t - 128, tt = o / V, v = o % V;
        const float* tr = &tg[tt * E];
        const float* gr = &Gs[v * E];
        float acc = cs[4 + v];
        #pragma unroll 5
        for (int k = 0; k < E; k += 4) {
            float4 a = *(const float4*)(tr + k);
            float4 g = *(const float4*)(gr + k);
            acc += a.x * g.x + a.y * g.y + a.z * g.z + a.w * g.w;
        }
        m2s[o] = acc;
    }
    __syncthreads();

    // ---- softmax over S per v (waves 0-2) ; softmax over T per v (wave 3) ----
    {
        int wv = t >> 6, lane = t & 63;
        if (wv < V) {
            float x1 = m1s[wv * S + lane];
            float x2 = (lane + 64 < S) ? m1s[wv * S + lane + 64] : -INFINITY;
            float mx = fmaxf(x1, x2);
            for (int d = 32; d > 0; d >>= 1) mx = fmaxf(mx, __shfl_xor(mx, d));
            float e1 = __expf(x1 - mx);
            float e2 = (lane + 64 < S) ? __expf(x2 - mx) : 0.f;
            float sm = e1 + e2;
            for (int d = 32; d > 0; d >>= 1) sm += __shfl_xor(sm, d);
            float inv = 1.f / sm;
            sm1s[wv * S + lane] = e1 * inv;
            if (lane + 64 < S) sm1s[wv * S + lane + 64] = e2 * inv;
        } else if (lane < V) {
            float mm[T];
            float mx = -INFINITY;
            for (int tt = 0; tt < T; ++tt) { mm[tt] = m2s[tt * V + lane]; mx = fmaxf(mx, mm[tt]); }
            float ee[T];
            float sum = 0.f;
            for (int tt = 0; tt < T; ++tt) { ee[tt] = __expf(mm[tt] - mx); sum += ee[tt]; }
            float inv = 1.f / sum;
            for (int tt = 0; tt < T; ++tt) sm2s[tt * V + lane] = ee[tt] * inv;
        }
    }
    __syncthreads();

    // ---- y[v][k] = sum_s sm1[v][s] * x[s][k]   (coalesced global re-read, L2-hot) ----
    for (int o = t; o < V * E; o += 256) {
        int v = o / E, k = o % E;
        const float* smr = &sm1s[v * S];
        const float* xc  = xb + k;
        float a0 = 0.f, a1 = 0.f;
        #pragma unroll 4
        for (int s = 0; s < S; s += 2) {
            a0 += smr[s]     * xc[s * E];
            a1 += smr[s + 1] * xc[(s + 1) * E];
        }
        ys[o] = a0 + a1;
    }
    __syncthreads();

    // ---- ws1[v][e] = b1[e] + y[v,:]·W1[e,:]   (W1 rows contiguous, L2-hot) ----
    for (int o = t; o < V * E; o += 256) {
        int v = o / E, e = o % E;
        const float* wr = fc1w + e * E;
        const float* yr = &ys[v * E];
        float acc = b1s[e];
        #pragma unroll 5
        for (int k = 0; k < E; k += 4) {
            float4 w  = *(const float4*)(wr + k);
            float4 yv = *(const float4*)(&yr[k]);
            acc += w.x * yv.x + w.y * yv.y + w.z * yv.z + w.w * yv.w;
        }
        ws1s[o] = acc;
    }
    __syncthreads();

    // ---- p3[t*3+v] = sm2[t][v] * (ws1[v,:]·tag[t,:]) ----
    if (t < T * V) {
        int tt = t / V, v = t % V;
        const float* wr = &ws1s[v * E];
        const float* tr = &tg[tt * E];
        float acc = 0.f;
        #pragma unroll 5
        for (int k = 0; k < E; k += 4) {
            float4 w = *(const float4*)(wr + k);
            float4 a = *(const float4*)(tr + k);
            acc += w.x * a.x + w.y * a.y + w.z * a.z + w.w * a.w;
        }
        p3[t] = sm2s[t] * acc;
    }
    __syncthreads();
    if (t < T)
        out[(size_t)b * T + t] = p3[t * V] + p3[t * V + 1] + p3[t * V + 2];
}

extern "C" void kernel_launch(void* const* d_in, const int* in_sizes, int n_in,
                              void* d_out, int out_size, void* d_ws, size_t ws_size,
                              hipStream_t stream) {
    const float* x    = (const float*)d_in[0];
    const float* tag  = (const float*)d_in[1];
    const float* vk   = (const float*)d_in[2];
    const float* fc1w = (const float*)d_in[3];
    const float* fc1b = (const float*)d_in[4];
    const float* fc2w = (const float*)d_in[5];
    const float* fc2b = (const float*)d_in[6];
    const float* fc3w = (const float*)d_in[7];
    const float* fc3b = (const float*)d_in[8];
    const float* fc4w = (const float*)d_in[9];
    const float* fc4b = (const float*)d_in[10];
    float* out = (float*)d_out;
    float* ws  = (float*)d_ws;

    hipLaunchKernelGGL(prep_kernel, dim3(2), dim3(256), 0, stream,
                       vk, fc1w, fc1b, fc2w, fc2b, fc3w, fc3b, fc4w, fc4b, ws);
    hipLaunchKernelGGL(mvke_main, dim3(NB), dim3(256), 0, stream,
                       x, tag, fc1w, ws, out);
}

// Round 5
// 558.618 us; speedup vs baseline: 1.1900x; 1.1900x over previous
//
#include <hip/hip_runtime.h>
#include <math.h>

#define E 100
#define V 3
#define S 100
#define T 10
#define NB 8192
#define SCALE 0.1f
#define PADV  (-4294967295.0f)

// ws float offsets (prep outputs) — total 716 floats
#define WS_H  0     // [3][100]  H = SCALE * (of2 @ W1)
#define WS_G  304   // [3][100]  G = SCALE * (of3 @ W4)
#define WS_B1 608   // [100]     fc1_b passthrough
#define WS_C1 708   // [3]       SCALE * of2·b1
#define WS_C2 712   // [3]       SCALE * of3·b4

// Async global->LDS, 16B per lane. LDS dest must be wave-uniform base + lane*16.
#define GLOAD_LDS16(g, l) __builtin_amdgcn_global_load_lds( \
    (const __attribute__((address_space(1))) void*)(g),      \
    (__attribute__((address_space(3))) void*)(l), 16, 0, 0)

// lgkm-only barrier: orders LDS writes across waves WITHOUT draining the
// async global_load_lds queue (vmcnt). __syncthreads() would drain vmcnt(0).
#define LGKM_BARRIER() do {                                   \
    asm volatile("s_waitcnt lgkmcnt(0)" ::: "memory");        \
    __builtin_amdgcn_s_barrier();                             \
    __builtin_amdgcn_sched_barrier(0);                        \
} while (0)

// Algebra: of1/of4 are never materialized.
//   m1[s,v]  = x[s,:]·H[v,:] + c1[v]          (masked -> PADV, softmax over s)
//   y[v,k]   = sum_s sm1[s,v] * x[s,k]
//   ws1[v,e] = y[v,:]·W1[e,:] + b1[e]          (sum_s sm1 == 1 exactly)
//   m2[t,v]  = tag[t,:]·G[v,:] + c2[v]         (softmax over t)
//   out[t]   = sum_v sm2[t,v] * (ws1[v,:]·tag[t,:])
//
// R4/R5: async fire-and-forget staging of x,tag into LDS (read-once traffic)
// while the m1 chain runs on global reads (L2-MSHR-merged with async stream).
// Raw s_barrier + lgkmcnt-only waits keep the async loads in flight across the
// m1/softmax phases; single vmcnt(0) drain right before the y-phase.

__global__ __launch_bounds__(256) void prep_kernel(const float* __restrict__ vk,
        const float* __restrict__ fc1w, const float* __restrict__ fc1b,
        const float* __restrict__ fc2w, const float* __restrict__ fc2b,
        const float* __restrict__ fc3w, const float* __restrict__ fc3b,
        const float* __restrict__ fc4w, const float* __restrict__ fc4b,
        float* __restrict__ ws)
{
    __shared__ __align__(16) float wsm[E * E];   // W1 (blk 0) or W4 (blk 1)
    __shared__ __align__(16) float ofs[V * E];   // of2 (blk 0) or of3 (blk 1)
    const int t   = threadIdx.x;
    const int blk = blockIdx.x;                  // 0: H/c1/b1 path, 1: G/c2 path
    const float* WA = blk ? fc4w : fc1w;
    const float* WB = blk ? fc3w : fc2w;
    const float* bB = blk ? fc3b : fc2b;
    const float* bA = blk ? fc4b : fc1b;

    for (int i = t; i < E * E / 4; i += 256)      // stage WA into LDS
        *(float4*)(&wsm[4 * i]) = *(const float4*)(WA + 4 * i);

    for (int o = t; o < V * E; o += 256) {        // of[v][e] = vk[v,:]·WB[e,:] + bB[e]
        int v = o / E, e = o % E;
        const float* vr = vk + v * E;
        const float* wr = WB + e * E;
        float acc = bB[e];
        for (int k = 0; k < E; k += 4) {
            float4 a = *(const float4*)(vr + k);
            float4 w = *(const float4*)(wr + k);
            acc += a.x * w.x + a.y * w.y + a.z * w.z + a.w * w.w;
        }
        ofs[o] = acc;
    }
    __syncthreads();

    for (int o = t; o < V * E; o += 256) {        // H/G[v][k] = SCALE * sum_e of[v][e]*WA[e][k]
        int v = o / E, k = o % E;
        float acc = 0.f;
        for (int e = 0; e < E; ++e) acc += ofs[v * E + e] * wsm[e * E + k];
        ws[(blk ? WS_G : WS_H) + o] = acc * SCALE;
    }
    if (t < V) {                                   // c[v] = SCALE * sum_e bA[e]*of[v][e]
        float acc = 0.f;
        for (int e = 0; e < E; ++e) acc += bA[e] * ofs[t * E + e];
        ws[(blk ? WS_C2 : WS_C1) + t] = acc * SCALE;
    }
    if (blk == 0 && t < E) ws[WS_B1 + t] = fc1b[t];
}

__global__ __launch_bounds__(256, 3) void mvke_main(const float* __restrict__ x,
        const float* __restrict__ tag, const float* __restrict__ fc1w,
        const float* __restrict__ ws, float* __restrict__ out)
{
    __shared__ __align__(16) float xs[S * E];      // 40000 B, linear (global_load_lds)
    __shared__ __align__(16) float tg[T * E];      // 4000 B
    __shared__ __align__(16) float Hs[V * E];
    __shared__ __align__(16) float Gs[V * E];
    __shared__ __align__(16) float b1s[E];
    __shared__ float cs[8];                         // c1 in [0..2], c2 in [4..6]
    __shared__ __align__(16) float m1s[V * S];     // [v][s]
    __shared__ __align__(16) float sm1s[V * S];    // [v][s]
    __shared__ __align__(16) float ys[V * E];      // [v][k]
    __shared__ __align__(16) float ws1s[V * E];    // [v][e]
    __shared__ float m2s[T * V];                    // [t*3+v]
    __shared__ float sm2s[T * V];
    __shared__ float p3[32];
    // total ~52 KB -> 3 blocks/CU (LDS-bound)

    const int t = threadIdx.x;
    const int b = blockIdx.x;
    const float* xb = x   + (size_t)b * (S * E);
    const float* tb = tag + (size_t)b * (T * E);

    // ---- fire-and-forget async staging: x = 2500 float4 chunks, tag = 250 ----
    #pragma unroll
    for (int j = 0; j < 9; ++j) {                  // chunks 0..2303
        int i = t + 256 * j;
        GLOAD_LDS16(xb + 4 * i, &xs[4 * i]);
    }
    if (t < 196) {                                 // chunks 2304..2499
        int i = t + 2304;
        GLOAD_LDS16(xb + 4 * i, &xs[4 * i]);
    }
    if (t < 250)                                   // tag chunks 0..249
        GLOAD_LDS16(tb + 4 * t, &tg[4 * t]);

    // ---- stage small precomputed arrays via regular loads (L2-hot) ----
    if (t < 75)        *(float4*)(&Hs[4 * t])          = *(const float4*)(ws + WS_H  + 4 * t);
    else if (t < 150)  *(float4*)(&Gs[4 * (t - 75)])   = *(const float4*)(ws + WS_G  + 4 * (t - 75));
    else if (t < 175)  *(float4*)(&b1s[4 * (t - 150)]) = *(const float4*)(ws + WS_B1 + 4 * (t - 150));
    else if (t < 183)  cs[t - 175] = ws[WS_C1 + (t - 175)];
    LGKM_BARRIER();                                // Hs/Gs/b1s/cs visible; async still in flight

    // ---- phase 1: m1 rows from GLOBAL x (MSHR-merged with async stream) ;
    //      m2 from GLOBAL tag on wave 2 ----
    if (t < S) {
        const float* xr = xb + t * E;
        float a0 = cs[0], a1 = cs[1], a2 = cs[2], ra = 0.f;
        #pragma unroll 5
        for (int k = 0; k < E; k += 4) {
            float4 xv = *(const float4*)(xr + k);
            float4 h0 = *(const float4*)(&Hs[k]);
            float4 h1 = *(const float4*)(&Hs[E + k]);
            float4 h2 = *(const float4*)(&Hs[2 * E + k]);
            a0 += xv.x * h0.x + xv.y * h0.y + xv.z * h0.z + xv.w * h0.w;
            a1 += xv.x * h1.x + xv.y * h1.y + xv.z * h1.z + xv.w * h1.w;
            a2 += xv.x * h2.x + xv.y * h2.y + xv.z * h2.z + xv.w * h2.w;
            ra += fabsf(xv.x) + fabsf(xv.y) + fabsf(xv.z) + fabsf(xv.w);
        }
        bool z = (ra == 0.f);
        m1s[t]         = z ? PADV : a0;
        m1s[S + t]     = z ? PADV : a1;
        m1s[2 * S + t] = z ? PADV : a2;
    } else if (t >= 128 && t < 128 + T * V) {
        int o = t - 128, tt = o / V, v = o % V;
        const float* tr = tb + tt * E;             // global (tg LDS not ready yet)
        const float* gr = &Gs[v * E];
        float acc = cs[4 + v];
        #pragma unroll 5
        for (int k = 0; k < E; k += 4) {
            float4 a = *(const float4*)(tr + k);
            float4 g = *(const float4*)(gr + k);
            acc += a.x * g.x + a.y * g.y + a.z * g.z + a.w * g.w;
        }
        m2s[o] = acc;
    }
    LGKM_BARRIER();                                // m1s/m2s visible; async still in flight

    // ---- softmax over S per v (waves 0-2) ; softmax over T per v (wave 3) ----
    {
        int wv = t >> 6, lane = t & 63;
        if (wv < V) {
            float x1 = m1s[wv * S + lane];
            float x2 = (lane + 64 < S) ? m1s[wv * S + lane + 64] : -INFINITY;
            float mx = fmaxf(x1, x2);
            for (int d = 32; d > 0; d >>= 1) mx = fmaxf(mx, __shfl_xor(mx, d));
            float e1 = __expf(x1 - mx);
            float e2 = (lane + 64 < S) ? __expf(x2 - mx) : 0.f;
            float sm = e1 + e2;
            for (int d = 32; d > 0; d >>= 1) sm += __shfl_xor(sm, d);
            float inv = 1.f / sm;
            sm1s[wv * S + lane] = e1 * inv;
            if (lane + 64 < S) sm1s[wv * S + lane + 64] = e2 * inv;
        } else if (lane < V) {
            float mm[T];
            float mx = -INFINITY;
            for (int tt = 0; tt < T; ++tt) { mm[tt] = m2s[tt * V + lane]; mx = fmaxf(mx, mm[tt]); }
            float ee[T];
            float sum = 0.f;
            for (int tt = 0; tt < T; ++tt) { ee[tt] = __expf(mm[tt] - mx); sum += ee[tt]; }
            float inv = 1.f / sum;
            for (int tt = 0; tt < T; ++tt) sm2s[tt * V + lane] = ee[tt] * inv;
        }
    }
    LGKM_BARRIER();                                // sm1s/sm2s visible

    // ---- drain async staging (own wave's loads), then barrier => xs/tg valid ----
    asm volatile("s_waitcnt vmcnt(0)" ::: "memory");
    __builtin_amdgcn_s_barrier();
    __builtin_amdgcn_sched_barrier(0);

    // ---- y[v][k] = sum_s sm1[v][s] * xs[s][k]  (LDS, lane=k consecutive: conflict-free) ----
    for (int o = t; o < V * E; o += 256) {
        int v = o / E, k = o % E;
        const float* smr = &sm1s[v * S];
        const float* xc  = &xs[k];
        float a0 = 0.f, a1 = 0.f, a2 = 0.f, a3 = 0.f;
        #pragma unroll 5
        for (int s = 0; s < S; s += 4) {
            a0 += smr[s]     * xc[s * E];
            a1 += smr[s + 1] * xc[(s + 1) * E];
            a2 += smr[s + 2] * xc[(s + 2) * E];
            a3 += smr[s + 3] * xc[(s + 3) * E];
        }
        ys[o] = (a0 + a1) + (a2 + a3);
    }
    __syncthreads();

    // ---- ws1[v][e] = b1[e] + y[v,:]·W1[e,:]   (W1 rows contiguous, L2-hot) ----
    for (int o = t; o < V * E; o += 256) {
        int v = o / E, e = o % E;
        const float* wr = fc1w + e * E;
        const float* yr = &ys[v * E];
        float acc = b1s[e];
        #pragma unroll 5
        for (int k = 0; k < E; k += 4) {
            float4 w  = *(const float4*)(wr + k);
            float4 yv = *(const float4*)(&yr[k]);
            acc += w.x * yv.x + w.y * yv.y + w.z * yv.z + w.w * yv.w;
        }
        ws1s[o] = acc;
    }
    __syncthreads();

    // ---- p3[t*3+v] = sm2[t][v] * (ws1[v,:]·tag[t,:]) ----
    if (t < T * V) {
        int tt = t / V, v = t % V;
        const float* wr = &ws1s[v * E];
        const float* tr = &tg[tt * E];
        float acc = 0.f;
        #pragma unroll 5
        for (int k = 0; k < E; k += 4) {
            float4 w = *(const float4*)(wr + k);
            float4 a = *(const float4*)(tr + k);
            acc += w.x * a.x + w.y * a.y + w.z * a.z + w.w * a.w;
        }
        p3[t] = sm2s[t] * acc;
    }
    __syncthreads();
    if (t < T)
        out[(size_t)b * T + t] = p3[t * V] + p3[t * V + 1] + p3[t * V + 2];
}

extern "C" void kernel_launch(void* const* d_in, const int* in_sizes, int n_in,
                              void* d_out, int out_size, void* d_ws, size_t ws_size,
                              hipStream_t stream) {
    const float* x    = (const float*)d_in[0];
    const float* tag  = (const float*)d_in[1];
    const float* vk   = (const float*)d_in[2];
    const float* fc1w = (const float*)d_in[3];
    const float* fc1b = (const float*)d_in[4];
    const float* fc2w = (const float*)d_in[5];
    const float* fc2b = (const float*)d_in[6];
    const float* fc3w = (const float*)d_in[7];
    const float* fc3b = (const float*)d_in[8];
    const float* fc4w = (const float*)d_in[9];
    const float* fc4b = (const float*)d_in[10];
    float* out = (float*)d_out;
    float* ws  = (float*)d_ws;

    hipLaunchKernelGGL(prep_kernel, dim3(2), dim3(256), 0, stream,
                       vk, fc1w, fc1b, fc2w, fc2b, fc3w, fc3b, fc4w, fc4b, ws);
    hipLaunchKernelGGL(mvke_main, dim3(NB), dim3(256), 0, stream,
                       x, tag, fc1w, ws, out);
}